// Round 13
// baseline (182.575 us; speedup 1.0000x reference)
//
#include <hip/hip_runtime.h>

// VQ: x (16,64,64,64) f32, codebook e (64,1024) f32. N=65536, D=64, K=1024.
//
// R19: R18 confirmed the codegen-perturbation theory (main 66->53.5us @ 72
// VGPR once the resolve was evicted), but the separate fallback costs ~19us:
// each ambiguous position's wave privately streams the 256KB codebook from
// L2 (~2048 items => 512MB aggregate). Fix: batch FOUR positions per wave,
// sharing one e-stream (R9 proved this sharing bit-exact with 2 positions
// over the entire output; per-position arithmetic unchanged: sequential-d
// FMA chain per code, pairwise-8 Ap, lane-major butterfly, np tie-breaks).
// Traffic 512MB -> 128MB. Tail guarded by has[] flags (writes suppressed).
// vq_prep / vq_main: R18-verbatim (vectorized x-stage + A-build from LDS,
// 32x32x16 12-MFMA loop, fmed3 top-2, merge, certify -> global worklist,
// vectorized STE write). Proven absmax 0.

#define D 64
#define K 1024
#define NPOS 65536
#define HW 4096
#define XSTRIDE 262144  // D*HW
#define MARGIN 1.0e-3f

typedef float vfloat4  __attribute__((ext_vector_type(4)));
typedef float vfloat16 __attribute__((ext_vector_type(16)));
typedef short short8   __attribute__((ext_vector_type(8)));

static __device__ __forceinline__ unsigned short bf16_rne(float f) {
    unsigned u = __float_as_uint(f);
    u += 0x7FFFu + ((u >> 16) & 1u);
    return (unsigned short)(u >> 16);
}
static __device__ __forceinline__ float bf16_to_f32(unsigned short h) {
    return __uint_as_float(((unsigned)h) << 16);
}

// ---- prep: codebook -> bf16 split 32x32-B-fragments + c2n = -0.5*sum(e^2) -
// frag layout: ebf[tile][ks][split][lane][j], value = split(e[d][k]),
// d = ks*16 + (lane>>5)*8 + j, k = tile*32 + (lane&31). Tile = 8 KB.
__global__ void vq_prep(const float* __restrict__ e,
                        unsigned short* __restrict__ ebf,
                        float* __restrict__ c2n,
                        int* __restrict__ wl_count) {
    const int tile = blockIdx.x;               // 0..31
    const int t = threadIdx.x;
    if (tile == 0 && t == 0) *wl_count = 0;    // ws re-poisoned every launch
    const int l = t & 63;
    const int ks = t >> 6;                     // 0..3
    const int k = tile * 32 + (l & 31);
#pragma unroll
    for (int j = 0; j < 8; ++j) {
        const int d = ks * 16 + (l >> 5) * 8 + j;
        const float v = e[d * K + k];
        const unsigned short hh = bf16_rne(v);
        const float rem = v - bf16_to_f32(hh);     // exact (Sterbenz)
        const unsigned short hl = bf16_rne(rem);
        ebf[((size_t)(tile * 8 + ks * 2 + 0) * 64 + l) * 8 + j] = hh;
        ebf[((size_t)(tile * 8 + ks * 2 + 1) * 64 + l) * 8 + j] = hl;
    }
    if (t < 32) {
        const int kk = tile * 32 + t;
        float s = 0.f;
#pragma unroll
        for (int d = 0; d < D; ++d) {
            const float v = e[d * K + kk];     // sequential-d rounded squares
            s = s + __fmul_rn(v, v);
        }
        c2n[kk] = -0.5f * s;
    }
}

// ---- main: 512 blocks x 256 threads; block = 128 positions, 4 waves -------
__global__ __launch_bounds__(256, 2)
void vq_main(const float* __restrict__ x, const float* __restrict__ e,
             const unsigned short* __restrict__ ebf,
             const float* __restrict__ c2n,
             float* __restrict__ out, int* __restrict__ wl_count,
             int* __restrict__ wl) {
    __shared__ __align__(16) float xt[64][128];              // 32 KB x-tile
    __shared__ __align__(16) unsigned short lds_e[2][4096];  // 2 x 8 KB tiles
    __shared__ int bk_lds[128];
    const int t = threadIdx.x;
    const int lane = t & 63;
    const int w = t >> 6;                      // wave 0..3 = position group
    const int p0 = blockIdx.x * 128;
    const int b = p0 >> 12;                    // 128 | 4096 -> single b
    const int sp0 = p0 & (HW - 1);
    const int c31 = lane & 31;                 // code column / A row
    const int hi = lane >> 5;                  // k-group half

    // ---- vectorized x-stage: float4 along sp, 512B/wave-op contiguous ----
    {
        const int spq = t & 31;                // sp quad 0..31
        const int d0 = t >> 5;                 // 0..7
        vfloat4 xs[8];
#pragma unroll
        for (int p = 0; p < 8; ++p) {          // d = p*8 + d0
            const int d = p * 8 + d0;
            xs[p] = *(const vfloat4*)(x + (size_t)b * XSTRIDE + (size_t)d * HW + sp0 + spq * 4);
        }
        // tile-0 ebf staging issued alongside (global -> reg)
        const short8 s0 = *(const short8*)(ebf + t * 8);
        const short8 s1v = *(const short8*)(ebf + 2048 + t * 8);
#pragma unroll
        for (int p = 0; p < 8; ++p)
            *(vfloat4*)(&xt[p * 8 + d0][spq * 4]) = xs[p];
        *(short8*)(&lds_e[0][t * 8]) = s0;
        *(short8*)(&lds_e[0][2048 + t * 8]) = s1v;
    }
    __syncthreads();                           // xt + tile0 in LDS

    // A-frags from LDS (bit-identical values): xh/xl for 4 K-steps (K=16)
    short8 ah[4], al[4];
    {
        const int pos = w * 32 + c31;          // this lane's position in tile
#pragma unroll
        for (int ks = 0; ks < 4; ++ks) {
            short8 fh, fl_;
#pragma unroll
            for (int j = 0; j < 8; ++j) {
                const int d = ks * 16 + hi * 8 + j;    // A[row=c31][k]
                const float v = xt[d][pos];
                const unsigned short h = bf16_rne(v);
                fh[j] = (short)h;
                fl_[j] = (short)bf16_rne(v - bf16_to_f32(h));
            }
            ah[ks] = fh; al[ks] = fl_;
        }
    }

    float s1[16], s2[16]; int t1[16];
#pragma unroll
    for (int r = 0; r < 16; ++r) { s1[r] = -3.4e38f; s2[r] = -3.4e38f; t1[r] = 0; }

    for (int tt = 0; tt < 32; ++tt) {
        const int cur = tt & 1;
        short8 stg0, stg1;
        if (tt < 31) {                         // issue early: hide L2 latency
            stg0 = *(const short8*)(ebf + (size_t)(tt + 1) * 4096 + t * 8);
            stg1 = *(const short8*)(ebf + (size_t)(tt + 1) * 4096 + 2048 + t * 8);
        }
        const short8* fb = (const short8*)(&lds_e[cur][0]);
        const float c2v = c2n[tt * 32 + c31];
        vfloat16 acc;
#pragma unroll
        for (int r = 0; r < 16; ++r) acc[r] = c2v;   // m = x.e - 0.5*c2
#pragma unroll
        for (int ks = 0; ks < 4; ++ks) {       // only 8 B-regs live at a time
            const short8 bh = fb[(ks * 2 + 0) * 64 + lane];
            const short8 bl = fb[(ks * 2 + 1) * 64 + lane];
            acc = __builtin_amdgcn_mfma_f32_32x32x16_bf16(ah[ks], bh, acc, 0, 0, 0);
            acc = __builtin_amdgcn_mfma_f32_32x32x16_bf16(al[ks], bh, acc, 0, 0, 0);
            acc = __builtin_amdgcn_mfma_f32_32x32x16_bf16(ah[ks], bl, acc, 0, 0, 0);
        }
#pragma unroll
        for (int r = 0; r < 16; ++r) {         // C/D: col=c31, row via r,hi
            const float m = acc[r];
            const bool gt = m > s1[r];
            s2[r] = __builtin_amdgcn_fmed3f(m, s1[r], s2[r]);  // second-best
            s1[r] = fmaxf(s1[r], m);
            t1[r] = gt ? tt : t1[r];
        }
        if (tt < 31) {                         // reg dep forces vmcnt wait
            *(short8*)(&lds_e[cur ^ 1][t * 8]) = stg0;
            *(short8*)(&lds_e[cur ^ 1][2048 + t * 8]) = stg1;
        }
        __syncthreads();                       // ds_write visible to all waves
    }

    // merge top-2 across the 32 code-columns (within each 32-lane half);
    // certify; push GLOBAL worklist. Lanes 0 and 32 own 16 positions each.
#pragma unroll
    for (int r = 0; r < 16; ++r) {
        float a1 = s1[r], a2 = s2[r];
        int ak = t1[r] * 32 + c31;
#pragma unroll
        for (int m = 1; m < 32; m <<= 1) {     // masks <32 stay in-half
            const float o1 = __shfl_xor(a1, m, 64);
            const float o2 = __shfl_xor(a2, m, 64);
            const int   ok = __shfl_xor(ak, m, 64);
            const bool take = (o1 > a1) || (o1 == a1 && ok < ak);
            const float loser = take ? a1 : o1;
            a1 = take ? o1 : a1;
            ak = take ? ok : ak;
            a2 = fmaxf(fmaxf(a2, o2), loser);
        }
        if (c31 == 0) {
            const int pl = w * 32 + (r & 3) + 8 * (r >> 2) + hi * 4;
            bk_lds[pl] = ak;
            if (a1 - a2 <= 0.5f * MARGIN) {    // score gap = 2*(m1-m2)
                const int idx = atomicAdd(wl_count, 1);
                wl[idx] = p0 + pl;
            }
        }
    }
    __syncthreads();

    // ---- vectorized STE write: thread = 4 consecutive sp x 8 channels ----
    // float4 x re-read (L2-hot), scalar e-gather (L2-resident), float4 store
    // (1 KB/wave-op). Per-element fl(x + fl(q-x)) unchanged => bit-exact.
    // (fallback overwrites the ambiguous positions afterwards, stream-order)
    {
        const int spq = t & 31;                // sp quad
        const int cg = t >> 5;                 // channel group 0..7
        const int pl0 = spq * 4;
        const int bk0 = bk_lds[pl0 + 0];
        const int bk1 = bk_lds[pl0 + 1];
        const int bk2 = bk_lds[pl0 + 2];
        const int bk3 = bk_lds[pl0 + 3];
        const size_t base = (size_t)b * XSTRIDE + sp0 + pl0;
#pragma unroll
        for (int i = 0; i < 8; ++i) {
            const int c = cg * 8 + i;
            const vfloat4 xq = *(const vfloat4*)(x + base + (size_t)c * HW);
            vfloat4 qv;
            qv[0] = e[c * K + bk0];
            qv[1] = e[c * K + bk1];
            qv[2] = e[c * K + bk2];
            qv[3] = e[c * K + bk3];
            vfloat4 o;
#pragma unroll
            for (int j = 0; j < 4; ++j)
                o[j] = xq[j] + (qv[j] - xq[j]);   // np STE: fl(x + fl(q-x))
            *(vfloat4*)(out + base + (size_t)c * HW) = o;
        }
    }
}

// ---- fallback: bit-exact np scan, FOUR positions per wave -----------------
// One shared e-stream serves 4 positions (R9-proven sharing, extended).
__global__ __launch_bounds__(256, 2)
void vq_fallback(const float* __restrict__ x, const float* __restrict__ e,
                 const float* __restrict__ c2n,
                 const int* __restrict__ wl_count, const int* __restrict__ wl,
                 float* __restrict__ out) {
    const int t = threadIdx.x;
    const int lane = t & 63;
    const int w = t >> 6;
    const int count = *wl_count;
    const int nq = (count + 3) >> 2;           // quads of worklist items
    for (int ip = blockIdx.x * 4 + w; ip < nq; ip += gridDim.x * 4) {
        const int i0 = ip * 4;
        bool has[4]; int bj[4], spj[4];
        float myx[4];
#pragma unroll
        for (int j = 0; j < 4; ++j) {
            has[j] = (i0 + j) < count;
            const int pos = wl[has[j] ? (i0 + j) : i0];
            bj[j] = pos >> 12; spj[j] = pos & (HW - 1);
            // lane holds channel d=lane of position j; broadcast via shfl
            myx[j] = x[(size_t)bj[j] * XSTRIDE + (size_t)lane * HW + spj[j]];
        }
        // Ap per position: np.sum(x**2) in numpy pairwise-8 order
        float Ap[4];
#pragma unroll
        for (int j = 0; j < 4; ++j) {
            float r8[8];
#pragma unroll
            for (int i1 = 0; i1 < 8; ++i1) {
                const float v = __shfl(myx[j], i1, 64);
                r8[i1] = __fmul_rn(v, v);
            }
#pragma unroll
            for (int jj = 1; jj < 8; ++jj)
#pragma unroll
                for (int i1 = 0; i1 < 8; ++i1) {
                    const float v = __shfl(myx[j], 8 * jj + i1, 64);
                    r8[i1] = r8[i1] + __fmul_rn(v, v);
                }
            Ap[j] = ((r8[0] + r8[1]) + (r8[2] + r8[3])) + ((r8[4] + r8[5]) + (r8[6] + r8[7]));
        }
        // 16 codes/lane (k = lane*16+m); sequential-d FMA chain per code;
        // ONE e-stream feeds all 4 positions' accumulators.
        float a0[16], a1v[16], a2v[16], a3[16];
#pragma unroll
        for (int m = 0; m < 16; ++m) { a0[m] = 0.f; a1v[m] = 0.f; a2v[m] = 0.f; a3[m] = 0.f; }
#pragma unroll 2
        for (int d = 0; d < D; ++d) {
            const float x0 = __shfl(myx[0], d, 64);
            const float x1 = __shfl(myx[1], d, 64);
            const float x2 = __shfl(myx[2], d, 64);
            const float x3 = __shfl(myx[3], d, 64);
            const vfloat4 e0 = *(const vfloat4*)(e + d * K + lane * 16);
            const vfloat4 e1 = *(const vfloat4*)(e + d * K + lane * 16 + 4);
            const vfloat4 e2 = *(const vfloat4*)(e + d * K + lane * 16 + 8);
            const vfloat4 e3 = *(const vfloat4*)(e + d * K + lane * 16 + 12);
#pragma unroll
            for (int c = 0; c < 4; ++c) {
                a0[c]      = __builtin_fmaf(x0, e0[c], a0[c]);
                a0[4 + c]  = __builtin_fmaf(x0, e1[c], a0[4 + c]);
                a0[8 + c]  = __builtin_fmaf(x0, e2[c], a0[8 + c]);
                a0[12 + c] = __builtin_fmaf(x0, e3[c], a0[12 + c]);
                a1v[c]      = __builtin_fmaf(x1, e0[c], a1v[c]);
                a1v[4 + c]  = __builtin_fmaf(x1, e1[c], a1v[4 + c]);
                a1v[8 + c]  = __builtin_fmaf(x1, e2[c], a1v[8 + c]);
                a1v[12 + c] = __builtin_fmaf(x1, e3[c], a1v[12 + c]);
                a2v[c]      = __builtin_fmaf(x2, e0[c], a2v[c]);
                a2v[4 + c]  = __builtin_fmaf(x2, e1[c], a2v[4 + c]);
                a2v[8 + c]  = __builtin_fmaf(x2, e2[c], a2v[8 + c]);
                a2v[12 + c] = __builtin_fmaf(x2, e3[c], a2v[12 + c]);
                a3[c]      = __builtin_fmaf(x3, e0[c], a3[c]);
                a3[4 + c]  = __builtin_fmaf(x3, e1[c], a3[4 + c]);
                a3[8 + c]  = __builtin_fmaf(x3, e2[c], a3[8 + c]);
                a3[12 + c] = __builtin_fmaf(x3, e3[c], a3[12 + c]);
            }
        }
        // selection + butterfly + write, per position (np tie-breaks)
#pragma unroll
        for (int j = 0; j < 4; ++j) {
            const float* aj = (j == 0) ? a0 : (j == 1) ? a1v : (j == 2) ? a2v : a3;
            float bs = 3.4e38f; int bk = 0x7fffffff;
#pragma unroll
            for (int m = 0; m < 16; ++m) {
                const int k = lane * 16 + m;       // ascending k per lane
                const float c2k = -2.0f * c2n[k];  // exact pow2 = np c2[k]
                const float sc = __builtin_fmaf(-2.f, aj[m], Ap[j]) + c2k;
                if (sc < bs || (sc == bs && k < bk)) { bs = sc; bk = k; }
            }
#pragma unroll
            for (int mm = 1; mm < 64; mm <<= 1) {  // lane-major k = global
                const float os = __shfl_xor(bs, mm, 64);
                const int   ok = __shfl_xor(bk, mm, 64);
                if (os < bs || (os == bs && ok < bk)) { bs = os; bk = ok; }
            }
            if (has[j]) {                      // lane = channel write
                const float qv = e[lane * K + bk];
                out[(size_t)bj[j] * XSTRIDE + (size_t)lane * HW + spj[j]] =
                    myx[j] + (qv - myx[j]);
            }
        }
    }
}

extern "C" void kernel_launch(void* const* d_in, const int* in_sizes, int n_in,
                              void* d_out, int out_size, void* d_ws, size_t ws_size,
                              hipStream_t stream) {
    const float* x = (const float*)d_in[0];
    const float* e = (const float*)d_in[1];
    float* out = (float*)d_out;

    char* ws = (char*)d_ws;                          // ~517 KB used
    unsigned short* ebf = (unsigned short*)ws;       // 256 KB B-fragments
    float* c2n = (float*)(ws + 262144);              // 4 KB  (-0.5*sum e^2)
    int* wl_count = (int*)(ws + 266240);             // 16 B
    int* wl = (int*)(ws + 266256);                   // 256 KB worklist

    vq_prep<<<32, 256, 0, stream>>>(e, ebf, c2n, wl_count);
    vq_main<<<NPOS / 128, 256, 0, stream>>>(x, e, ebf, c2n, out, wl_count, wl);
    vq_fallback<<<512, 256, 0, stream>>>(x, e, c2n, wl_count, wl, out);
}

// Round 14
// 140.336 us; speedup vs baseline: 1.3010x; 1.3010x over previous
//
#include <hip/hip_runtime.h>

// VQ: x (16,64,64,64) f32, codebook e (64,1024) f32. N=65536, D=64, K=1024.
//
// R20: R19 post-mortem: 4-per-wave fallback batching was right on traffic
// (1.7GB -> 422MB) but the `const float* aj = (j==0)? a0 : ...` pointer
// TOOK THE ADDRESS of the accumulator arrays => all four a*[16] went to
// scratch (rule #20), VGPR pinned at the 128 cap, 95-160us of serialized
// scratch traffic. Fix, scratch eliminated:
//  - selection/butterfly/write macro-expanded 4x with the array NAME
//    substituted textually (every index compile-time-constant => registers);
//  - __launch_bounds__(256,1): VGPR cap 256 (need ~120), no forced spills.
// Per-position arithmetic byte-identical to R13/R19 (sequential-d FMA chain
// per code, pairwise-8 Ap, lane-major butterfly, np tie-breaks): bit-exact.
// vq_prep / vq_main: R18-verbatim (main proven 53.5us @ 72 VGPR, absmax 0).

#define D 64
#define K 1024
#define NPOS 65536
#define HW 4096
#define XSTRIDE 262144  // D*HW
#define MARGIN 1.0e-3f

typedef float vfloat4  __attribute__((ext_vector_type(4)));
typedef float vfloat16 __attribute__((ext_vector_type(16)));
typedef short short8   __attribute__((ext_vector_type(8)));

static __device__ __forceinline__ unsigned short bf16_rne(float f) {
    unsigned u = __float_as_uint(f);
    u += 0x7FFFu + ((u >> 16) & 1u);
    return (unsigned short)(u >> 16);
}
static __device__ __forceinline__ float bf16_to_f32(unsigned short h) {
    return __uint_as_float(((unsigned)h) << 16);
}

// ---- prep: codebook -> bf16 split 32x32-B-fragments + c2n = -0.5*sum(e^2) -
// frag layout: ebf[tile][ks][split][lane][j], value = split(e[d][k]),
// d = ks*16 + (lane>>5)*8 + j, k = tile*32 + (lane&31). Tile = 8 KB.
__global__ void vq_prep(const float* __restrict__ e,
                        unsigned short* __restrict__ ebf,
                        float* __restrict__ c2n,
                        int* __restrict__ wl_count) {
    const int tile = blockIdx.x;               // 0..31
    const int t = threadIdx.x;
    if (tile == 0 && t == 0) *wl_count = 0;    // ws re-poisoned every launch
    const int l = t & 63;
    const int ks = t >> 6;                     // 0..3
    const int k = tile * 32 + (l & 31);
#pragma unroll
    for (int j = 0; j < 8; ++j) {
        const int d = ks * 16 + (l >> 5) * 8 + j;
        const float v = e[d * K + k];
        const unsigned short hh = bf16_rne(v);
        const float rem = v - bf16_to_f32(hh);     // exact (Sterbenz)
        const unsigned short hl = bf16_rne(rem);
        ebf[((size_t)(tile * 8 + ks * 2 + 0) * 64 + l) * 8 + j] = hh;
        ebf[((size_t)(tile * 8 + ks * 2 + 1) * 64 + l) * 8 + j] = hl;
    }
    if (t < 32) {
        const int kk = tile * 32 + t;
        float s = 0.f;
#pragma unroll
        for (int d = 0; d < D; ++d) {
            const float v = e[d * K + kk];     // sequential-d rounded squares
            s = s + __fmul_rn(v, v);
        }
        c2n[kk] = -0.5f * s;
    }
}

// ---- main: 512 blocks x 256 threads; block = 128 positions, 4 waves -------
__global__ __launch_bounds__(256, 2)
void vq_main(const float* __restrict__ x, const float* __restrict__ e,
             const unsigned short* __restrict__ ebf,
             const float* __restrict__ c2n,
             float* __restrict__ out, int* __restrict__ wl_count,
             int* __restrict__ wl) {
    __shared__ __align__(16) float xt[64][128];              // 32 KB x-tile
    __shared__ __align__(16) unsigned short lds_e[2][4096];  // 2 x 8 KB tiles
    __shared__ int bk_lds[128];
    const int t = threadIdx.x;
    const int lane = t & 63;
    const int w = t >> 6;                      // wave 0..3 = position group
    const int p0 = blockIdx.x * 128;
    const int b = p0 >> 12;                    // 128 | 4096 -> single b
    const int sp0 = p0 & (HW - 1);
    const int c31 = lane & 31;                 // code column / A row
    const int hi = lane >> 5;                  // k-group half

    // ---- vectorized x-stage: float4 along sp, 512B/wave-op contiguous ----
    {
        const int spq = t & 31;                // sp quad 0..31
        const int d0 = t >> 5;                 // 0..7
        vfloat4 xs[8];
#pragma unroll
        for (int p = 0; p < 8; ++p) {          // d = p*8 + d0
            const int d = p * 8 + d0;
            xs[p] = *(const vfloat4*)(x + (size_t)b * XSTRIDE + (size_t)d * HW + sp0 + spq * 4);
        }
        // tile-0 ebf staging issued alongside (global -> reg)
        const short8 s0 = *(const short8*)(ebf + t * 8);
        const short8 s1v = *(const short8*)(ebf + 2048 + t * 8);
#pragma unroll
        for (int p = 0; p < 8; ++p)
            *(vfloat4*)(&xt[p * 8 + d0][spq * 4]) = xs[p];
        *(short8*)(&lds_e[0][t * 8]) = s0;
        *(short8*)(&lds_e[0][2048 + t * 8]) = s1v;
    }
    __syncthreads();                           // xt + tile0 in LDS

    // A-frags from LDS (bit-identical values): xh/xl for 4 K-steps (K=16)
    short8 ah[4], al[4];
    {
        const int pos = w * 32 + c31;          // this lane's position in tile
#pragma unroll
        for (int ks = 0; ks < 4; ++ks) {
            short8 fh, fl_;
#pragma unroll
            for (int j = 0; j < 8; ++j) {
                const int d = ks * 16 + hi * 8 + j;    // A[row=c31][k]
                const float v = xt[d][pos];
                const unsigned short h = bf16_rne(v);
                fh[j] = (short)h;
                fl_[j] = (short)bf16_rne(v - bf16_to_f32(h));
            }
            ah[ks] = fh; al[ks] = fl_;
        }
    }

    float s1[16], s2[16]; int t1[16];
#pragma unroll
    for (int r = 0; r < 16; ++r) { s1[r] = -3.4e38f; s2[r] = -3.4e38f; t1[r] = 0; }

    for (int tt = 0; tt < 32; ++tt) {
        const int cur = tt & 1;
        short8 stg0, stg1;
        if (tt < 31) {                         // issue early: hide L2 latency
            stg0 = *(const short8*)(ebf + (size_t)(tt + 1) * 4096 + t * 8);
            stg1 = *(const short8*)(ebf + (size_t)(tt + 1) * 4096 + 2048 + t * 8);
        }
        const short8* fb = (const short8*)(&lds_e[cur][0]);
        const float c2v = c2n[tt * 32 + c31];
        vfloat16 acc;
#pragma unroll
        for (int r = 0; r < 16; ++r) acc[r] = c2v;   // m = x.e - 0.5*c2
#pragma unroll
        for (int ks = 0; ks < 4; ++ks) {       // only 8 B-regs live at a time
            const short8 bh = fb[(ks * 2 + 0) * 64 + lane];
            const short8 bl = fb[(ks * 2 + 1) * 64 + lane];
            acc = __builtin_amdgcn_mfma_f32_32x32x16_bf16(ah[ks], bh, acc, 0, 0, 0);
            acc = __builtin_amdgcn_mfma_f32_32x32x16_bf16(al[ks], bh, acc, 0, 0, 0);
            acc = __builtin_amdgcn_mfma_f32_32x32x16_bf16(ah[ks], bl, acc, 0, 0, 0);
        }
#pragma unroll
        for (int r = 0; r < 16; ++r) {         // C/D: col=c31, row via r,hi
            const float m = acc[r];
            const bool gt = m > s1[r];
            s2[r] = __builtin_amdgcn_fmed3f(m, s1[r], s2[r]);  // second-best
            s1[r] = fmaxf(s1[r], m);
            t1[r] = gt ? tt : t1[r];
        }
        if (tt < 31) {                         // reg dep forces vmcnt wait
            *(short8*)(&lds_e[cur ^ 1][t * 8]) = stg0;
            *(short8*)(&lds_e[cur ^ 1][2048 + t * 8]) = stg1;
        }
        __syncthreads();                       // ds_write visible to all waves
    }

    // merge top-2 across the 32 code-columns (within each 32-lane half);
    // certify; push GLOBAL worklist. Lanes 0 and 32 own 16 positions each.
#pragma unroll
    for (int r = 0; r < 16; ++r) {
        float a1 = s1[r], a2 = s2[r];
        int ak = t1[r] * 32 + c31;
#pragma unroll
        for (int m = 1; m < 32; m <<= 1) {     // masks <32 stay in-half
            const float o1 = __shfl_xor(a1, m, 64);
            const float o2 = __shfl_xor(a2, m, 64);
            const int   ok = __shfl_xor(ak, m, 64);
            const bool take = (o1 > a1) || (o1 == a1 && ok < ak);
            const float loser = take ? a1 : o1;
            a1 = take ? o1 : a1;
            ak = take ? ok : ak;
            a2 = fmaxf(fmaxf(a2, o2), loser);
        }
        if (c31 == 0) {
            const int pl = w * 32 + (r & 3) + 8 * (r >> 2) + hi * 4;
            bk_lds[pl] = ak;
            if (a1 - a2 <= 0.5f * MARGIN) {    // score gap = 2*(m1-m2)
                const int idx = atomicAdd(wl_count, 1);
                wl[idx] = p0 + pl;
            }
        }
    }
    __syncthreads();

    // ---- vectorized STE write: thread = 4 consecutive sp x 8 channels ----
    // float4 x re-read (L2-hot), scalar e-gather (L2-resident), float4 store
    // (1 KB/wave-op). Per-element fl(x + fl(q-x)) unchanged => bit-exact.
    // (fallback overwrites the ambiguous positions afterwards, stream-order)
    {
        const int spq = t & 31;                // sp quad
        const int cg = t >> 5;                 // channel group 0..7
        const int pl0 = spq * 4;
        const int bk0 = bk_lds[pl0 + 0];
        const int bk1 = bk_lds[pl0 + 1];
        const int bk2 = bk_lds[pl0 + 2];
        const int bk3 = bk_lds[pl0 + 3];
        const size_t base = (size_t)b * XSTRIDE + sp0 + pl0;
#pragma unroll
        for (int i = 0; i < 8; ++i) {
            const int c = cg * 8 + i;
            const vfloat4 xq = *(const vfloat4*)(x + base + (size_t)c * HW);
            vfloat4 qv;
            qv[0] = e[c * K + bk0];
            qv[1] = e[c * K + bk1];
            qv[2] = e[c * K + bk2];
            qv[3] = e[c * K + bk3];
            vfloat4 o;
#pragma unroll
            for (int j = 0; j < 4; ++j)
                o[j] = xq[j] + (qv[j] - xq[j]);   // np STE: fl(x + fl(q-x))
            *(vfloat4*)(out + base + (size_t)c * HW) = o;
        }
    }
}

// ---- fallback: bit-exact np scan, FOUR positions per wave, ZERO scratch ---
// One shared e-stream serves 4 positions. All accumulators in registers:
// selection is macro-expanded per array name (no pointers to locals).
#define RESOLVE_POS(J, AJ)                                                  \
    {                                                                       \
        float bs = 3.4e38f; int bk = 0x7fffffff;                            \
        _Pragma("unroll")                                                   \
        for (int m = 0; m < 16; ++m) {                                      \
            const int k = lane * 16 + m;          /* ascending k per lane */\
            const float c2k = -2.0f * c2n[k];     /* exact pow2 = np c2 */  \
            const float sc = __builtin_fmaf(-2.f, AJ[m], Ap[J]) + c2k;      \
            if (sc < bs || (sc == bs && k < bk)) { bs = sc; bk = k; }       \
        }                                                                   \
        _Pragma("unroll")                                                   \
        for (int mm = 1; mm < 64; mm <<= 1) {     /* lane-major k order */  \
            const float os = __shfl_xor(bs, mm, 64);                        \
            const int   ok = __shfl_xor(bk, mm, 64);                        \
            if (os < bs || (os == bs && ok < bk)) { bs = os; bk = ok; }     \
        }                                                                   \
        if (has[J]) {                             /* lane = channel write */\
            const float qv = e[lane * K + bk];                              \
            out[(size_t)bj[J] * XSTRIDE + (size_t)lane * HW + spj[J]] =     \
                myx[J] + (qv - myx[J]);                                     \
        }                                                                   \
    }

__global__ __launch_bounds__(256, 1)
void vq_fallback(const float* __restrict__ x, const float* __restrict__ e,
                 const float* __restrict__ c2n,
                 const int* __restrict__ wl_count, const int* __restrict__ wl,
                 float* __restrict__ out) {
    const int t = threadIdx.x;
    const int lane = t & 63;
    const int w = t >> 6;
    const int count = *wl_count;
    const int nq = (count + 3) >> 2;           // quads of worklist items
    for (int ip = blockIdx.x * 4 + w; ip < nq; ip += gridDim.x * 4) {
        const int i0 = ip * 4;
        bool has[4]; int bj[4], spj[4];
        float myx[4];
#pragma unroll
        for (int j = 0; j < 4; ++j) {
            has[j] = (i0 + j) < count;
            const int pos = wl[has[j] ? (i0 + j) : i0];
            bj[j] = pos >> 12; spj[j] = pos & (HW - 1);
            // lane holds channel d=lane of position j; broadcast via shfl
            myx[j] = x[(size_t)bj[j] * XSTRIDE + (size_t)lane * HW + spj[j]];
        }
        // Ap per position: np.sum(x**2) in numpy pairwise-8 order
        float Ap[4];
#pragma unroll
        for (int j = 0; j < 4; ++j) {
            float r8[8];
#pragma unroll
            for (int i1 = 0; i1 < 8; ++i1) {
                const float v = __shfl(myx[j], i1, 64);
                r8[i1] = __fmul_rn(v, v);
            }
#pragma unroll
            for (int jj = 1; jj < 8; ++jj)
#pragma unroll
                for (int i1 = 0; i1 < 8; ++i1) {
                    const float v = __shfl(myx[j], 8 * jj + i1, 64);
                    r8[i1] = r8[i1] + __fmul_rn(v, v);
                }
            Ap[j] = ((r8[0] + r8[1]) + (r8[2] + r8[3])) + ((r8[4] + r8[5]) + (r8[6] + r8[7]));
        }
        // 16 codes/lane (k = lane*16+m); sequential-d FMA chain per code;
        // ONE e-stream feeds all 4 positions' register accumulators.
        float a0[16], a1v[16], a2v[16], a3[16];
#pragma unroll
        for (int m = 0; m < 16; ++m) { a0[m] = 0.f; a1v[m] = 0.f; a2v[m] = 0.f; a3[m] = 0.f; }
#pragma unroll 2
        for (int d = 0; d < D; ++d) {
            const float x0 = __shfl(myx[0], d, 64);
            const float x1 = __shfl(myx[1], d, 64);
            const float x2 = __shfl(myx[2], d, 64);
            const float x3 = __shfl(myx[3], d, 64);
            const vfloat4 e0 = *(const vfloat4*)(e + d * K + lane * 16);
            const vfloat4 e1 = *(const vfloat4*)(e + d * K + lane * 16 + 4);
            const vfloat4 e2 = *(const vfloat4*)(e + d * K + lane * 16 + 8);
            const vfloat4 e3 = *(const vfloat4*)(e + d * K + lane * 16 + 12);
#pragma unroll
            for (int c = 0; c < 4; ++c) {
                a0[c]      = __builtin_fmaf(x0, e0[c], a0[c]);
                a0[4 + c]  = __builtin_fmaf(x0, e1[c], a0[4 + c]);
                a0[8 + c]  = __builtin_fmaf(x0, e2[c], a0[8 + c]);
                a0[12 + c] = __builtin_fmaf(x0, e3[c], a0[12 + c]);
                a1v[c]      = __builtin_fmaf(x1, e0[c], a1v[c]);
                a1v[4 + c]  = __builtin_fmaf(x1, e1[c], a1v[4 + c]);
                a1v[8 + c]  = __builtin_fmaf(x1, e2[c], a1v[8 + c]);
                a1v[12 + c] = __builtin_fmaf(x1, e3[c], a1v[12 + c]);
                a2v[c]      = __builtin_fmaf(x2, e0[c], a2v[c]);
                a2v[4 + c]  = __builtin_fmaf(x2, e1[c], a2v[4 + c]);
                a2v[8 + c]  = __builtin_fmaf(x2, e2[c], a2v[8 + c]);
                a2v[12 + c] = __builtin_fmaf(x2, e3[c], a2v[12 + c]);
                a3[c]      = __builtin_fmaf(x3, e0[c], a3[c]);
                a3[4 + c]  = __builtin_fmaf(x3, e1[c], a3[4 + c]);
                a3[8 + c]  = __builtin_fmaf(x3, e2[c], a3[8 + c]);
                a3[12 + c] = __builtin_fmaf(x3, e3[c], a3[12 + c]);
            }
        }
        // selection + butterfly + write per position (np tie-breaks), with
        // the accumulator ARRAY NAME macro-substituted (registers, no aj*)
        RESOLVE_POS(0, a0)
        RESOLVE_POS(1, a1v)
        RESOLVE_POS(2, a2v)
        RESOLVE_POS(3, a3)
    }
}

extern "C" void kernel_launch(void* const* d_in, const int* in_sizes, int n_in,
                              void* d_out, int out_size, void* d_ws, size_t ws_size,
                              hipStream_t stream) {
    const float* x = (const float*)d_in[0];
    const float* e = (const float*)d_in[1];
    float* out = (float*)d_out;

    char* ws = (char*)d_ws;                          // ~517 KB used
    unsigned short* ebf = (unsigned short*)ws;       // 256 KB B-fragments
    float* c2n = (float*)(ws + 262144);              // 4 KB  (-0.5*sum e^2)
    int* wl_count = (int*)(ws + 266240);             // 16 B
    int* wl = (int*)(ws + 266256);                   // 256 KB worklist

    vq_prep<<<32, 256, 0, stream>>>(e, ebf, c2n, wl_count);
    vq_main<<<NPOS / 128, 256, 0, stream>>>(x, e, ebf, c2n, out, wl_count, wl);
    vq_fallback<<<512, 256, 0, stream>>>(x, e, c2n, wl_count, wl, out);
}

// Round 15
// 139.886 us; speedup vs baseline: 1.3052x; 1.0032x over previous
//
#include <hip/hip_runtime.h>

// VQ: x (16,64,64,64) f32, codebook e (64,1024) f32. N=65536, D=64, K=1024.
//
// R21: bookkeeping across R13-R20: overhead ~56us, prep ~4, main 52.5-53.5
// (13 falsified theories), exact-resolve ~13-27us in EVERY shape (inline
// 1/wave 13, separate 19, batched 27) because ~6600 uncertified positions
// rescan all 1024 codes. Fix: O(2) resolve via TOP-3 tracking:
//  - loop: s3 = fmed3(m, s2, s3) cascade (exact 3rd-best); t2 index tracked.
//  - merge: top-3 + 2 indices via 6-value sorting network in the butterfly.
//  - classify: gap12 > thr -> certified (unchanged, proven).
//    gap12 <= thr < gap13 -> true argmin in {k1,k2} (any other code is
//      > thr below a1; per-score error <= thr/2 -- same bound as the
//      certificate): exact np-score JUST k1,k2 (128 FMAs), inline, ~free.
//    gap13 <= thr (~1%, incl. all equal-score ties which the med3 cascade
//      routes here) -> R12-proven block-cooperative full scan, inline.
//  - third kernel + global worklist DELETED (2 kernels total).
// Exact-resolve arithmetic is verbatim-proven np math (sequential-d FMA
// chain, pairwise-8 Ap, -2*c2n scale, ascending-k tie-breaks).
// vq_main tile loop / staging / STE write: R20-verbatim (proven absmax 0).

#define D 64
#define K 1024
#define NPOS 65536
#define HW 4096
#define XSTRIDE 262144  // D*HW
#define MARGIN 1.0e-3f

typedef float vfloat4  __attribute__((ext_vector_type(4)));
typedef float vfloat16 __attribute__((ext_vector_type(16)));
typedef short short8   __attribute__((ext_vector_type(8)));

static __device__ __forceinline__ unsigned short bf16_rne(float f) {
    unsigned u = __float_as_uint(f);
    u += 0x7FFFu + ((u >> 16) & 1u);
    return (unsigned short)(u >> 16);
}
static __device__ __forceinline__ float bf16_to_f32(unsigned short h) {
    return __uint_as_float(((unsigned)h) << 16);
}

// ---- prep: codebook -> bf16 split 32x32-B-fragments + c2n = -0.5*sum(e^2) -
// frag layout: ebf[tile][ks][split][lane][j], value = split(e[d][k]),
// d = ks*16 + (lane>>5)*8 + j, k = tile*32 + (lane&31). Tile = 8 KB.
__global__ void vq_prep(const float* __restrict__ e,
                        unsigned short* __restrict__ ebf,
                        float* __restrict__ c2n) {
    const int tile = blockIdx.x;               // 0..31
    const int t = threadIdx.x;
    const int l = t & 63;
    const int ks = t >> 6;                     // 0..3
    const int k = tile * 32 + (l & 31);
#pragma unroll
    for (int j = 0; j < 8; ++j) {
        const int d = ks * 16 + (l >> 5) * 8 + j;
        const float v = e[d * K + k];
        const unsigned short hh = bf16_rne(v);
        const float rem = v - bf16_to_f32(hh);     // exact (Sterbenz)
        const unsigned short hl = bf16_rne(rem);
        ebf[((size_t)(tile * 8 + ks * 2 + 0) * 64 + l) * 8 + j] = hh;
        ebf[((size_t)(tile * 8 + ks * 2 + 1) * 64 + l) * 8 + j] = hl;
    }
    if (t < 32) {
        const int kk = tile * 32 + t;
        float s = 0.f;
#pragma unroll
        for (int d = 0; d < D; ++d) {
            const float v = e[d * K + kk];     // sequential-d rounded squares
            s = s + __fmul_rn(v, v);
        }
        c2n[kk] = -0.5f * s;
    }
}

// ---- main: 512 blocks x 256 threads; block = 128 positions, 4 waves -------
__global__ __launch_bounds__(256, 2)
void vq_main(const float* __restrict__ x, const float* __restrict__ e,
             const unsigned short* __restrict__ ebf,
             const float* __restrict__ c2n,
             float* __restrict__ out) {
    __shared__ __align__(16) float xt[64][128];              // 32 KB x-tile
    __shared__ __align__(16) unsigned short lds_e[2][4096];  // 2 x 8 KB tiles
    __shared__ int bk_lds[128];
    __shared__ int pw_pl[128];                 // pairwise worklist
    __shared__ int pw_kk[128];                 // k1 | k2<<16
    __shared__ int fs_pl[128];                 // full-scan worklist
    __shared__ int pw_cnt, fs_cnt;
    const int t = threadIdx.x;
    const int lane = t & 63;
    const int w = t >> 6;                      // wave 0..3 = position group
    const int p0 = blockIdx.x * 128;
    const int b = p0 >> 12;                    // 128 | 4096 -> single b
    const int sp0 = p0 & (HW - 1);
    const int c31 = lane & 31;                 // code column / A row
    const int hi = lane >> 5;                  // k-group half

    if (t == 0) { pw_cnt = 0; fs_cnt = 0; }

    // ---- vectorized x-stage: float4 along sp, 512B/wave-op contiguous ----
    {
        const int spq = t & 31;                // sp quad 0..31
        const int d0 = t >> 5;                 // 0..7
        vfloat4 xs[8];
#pragma unroll
        for (int p = 0; p < 8; ++p) {          // d = p*8 + d0
            const int d = p * 8 + d0;
            xs[p] = *(const vfloat4*)(x + (size_t)b * XSTRIDE + (size_t)d * HW + sp0 + spq * 4);
        }
        // tile-0 ebf staging issued alongside (global -> reg)
        const short8 s0 = *(const short8*)(ebf + t * 8);
        const short8 s1v = *(const short8*)(ebf + 2048 + t * 8);
#pragma unroll
        for (int p = 0; p < 8; ++p)
            *(vfloat4*)(&xt[p * 8 + d0][spq * 4]) = xs[p];
        *(short8*)(&lds_e[0][t * 8]) = s0;
        *(short8*)(&lds_e[0][2048 + t * 8]) = s1v;
    }
    __syncthreads();                           // xt + tile0 in LDS + counts=0

    // A-frags from LDS (bit-identical values): xh/xl for 4 K-steps (K=16)
    short8 ah[4], al[4];
    {
        const int pos = w * 32 + c31;          // this lane's position in tile
#pragma unroll
        for (int ks = 0; ks < 4; ++ks) {
            short8 fh, fl_;
#pragma unroll
            for (int j = 0; j < 8; ++j) {
                const int d = ks * 16 + hi * 8 + j;    // A[row=c31][k]
                const float v = xt[d][pos];
                const unsigned short h = bf16_rne(v);
                fh[j] = (short)h;
                fl_[j] = (short)bf16_rne(v - bf16_to_f32(h));
            }
            ah[ks] = fh; al[ks] = fl_;
        }
    }

    float s1[16], s2[16], s3[16]; int t1[16], t2[16];
#pragma unroll
    for (int r = 0; r < 16; ++r) {
        s1[r] = -3.4e38f; s2[r] = -3.4e38f; s3[r] = -3.4e38f;
        t1[r] = 0; t2[r] = 0;
    }

    for (int tt = 0; tt < 32; ++tt) {
        const int cur = tt & 1;
        short8 stg0, stg1;
        if (tt < 31) {                         // issue early: hide L2 latency
            stg0 = *(const short8*)(ebf + (size_t)(tt + 1) * 4096 + t * 8);
            stg1 = *(const short8*)(ebf + (size_t)(tt + 1) * 4096 + 2048 + t * 8);
        }
        const short8* fb = (const short8*)(&lds_e[cur][0]);
        const float c2v = c2n[tt * 32 + c31];
        vfloat16 acc;
#pragma unroll
        for (int r = 0; r < 16; ++r) acc[r] = c2v;   // m = x.e - 0.5*c2
#pragma unroll
        for (int ks = 0; ks < 4; ++ks) {       // only 8 B-regs live at a time
            const short8 bh = fb[(ks * 2 + 0) * 64 + lane];
            const short8 bl = fb[(ks * 2 + 1) * 64 + lane];
            acc = __builtin_amdgcn_mfma_f32_32x32x16_bf16(ah[ks], bh, acc, 0, 0, 0);
            acc = __builtin_amdgcn_mfma_f32_32x32x16_bf16(al[ks], bh, acc, 0, 0, 0);
            acc = __builtin_amdgcn_mfma_f32_32x32x16_bf16(ah[ks], bl, acc, 0, 0, 0);
        }
#pragma unroll
        for (int r = 0; r < 16; ++r) {         // C/D: col=c31, row via r,hi
            const float m = acc[r];
            const bool gt1 = m > s1[r];
            const bool gt2 = m > s2[r];
            // top-3 cascade: med3 with OLD s2 gives exact third-best
            s3[r] = __builtin_amdgcn_fmed3f(m, s2[r], s3[r]);
            s2[r] = __builtin_amdgcn_fmed3f(m, s1[r], s2[r]);
            s1[r] = fmaxf(s1[r], m);
            t2[r] = gt1 ? t1[r] : (gt2 ? tt : t2[r]);
            t1[r] = gt1 ? tt : t1[r];
        }
        if (tt < 31) {                         // reg dep forces vmcnt wait
            *(short8*)(&lds_e[cur ^ 1][t * 8]) = stg0;
            *(short8*)(&lds_e[cur ^ 1][2048 + t * 8]) = stg1;
        }
        __syncthreads();                       // ds_write visible to all waves
    }

    // merge top-3 + 2 indices across the 32 code-columns (in-half butterfly,
    // 6-value sorting network per step); classify; push local worklists.
#pragma unroll
    for (int r = 0; r < 16; ++r) {
        float a1 = s1[r], a2 = s2[r], a3 = s3[r];
        int k1v = t1[r] * 32 + c31;
        int k2v = t2[r] * 32 + c31;
#pragma unroll
        for (int m = 1; m < 32; m <<= 1) {     // masks <32 stay in-half
            const float o1 = __shfl_xor(a1, m, 64);
            const float o2 = __shfl_xor(a2, m, 64);
            const float o3 = __shfl_xor(a3, m, 64);
            const int  ok1 = __shfl_xor(k1v, m, 64);
            const int  ok2 = __shfl_xor(k2v, m, 64);
            const bool t1w = (o1 > a1) || (o1 == a1 && ok1 < k1v);
            const float w1 = t1w ? o1 : a1;  const int wk1 = t1w ? ok1 : k1v;
            const float Lv = t1w ? a1 : o1;  const int Lk  = t1w ? k1v : ok1;
            const float L2 = t1w ? a2 : o2;  // loser list's second
            const float W2 = t1w ? o2 : a2;  const int Wk2 = t1w ? ok2 : k2v;
            const float W3 = t1w ? o3 : a3;  // winner list's third
            const bool t2w = (Lv > W2) || (Lv == W2 && Lk < Wk2);
            a2 = t2w ? Lv : W2;  k2v = t2w ? Lk : Wk2;
            a3 = t2w ? fmaxf(W2, L2) : fmaxf(W3, Lv);
            a1 = w1; k1v = wk1;
        }
        if (c31 == 0) {
            const int pl = w * 32 + (r & 3) + 8 * (r >> 2) + hi * 4;
            bk_lds[pl] = k1v;
            if (a1 - a2 <= 0.5f * MARGIN) {    // uncertified
                if (a1 - a3 > 0.5f * MARGIN) { // argmin provably in {k1,k2}
                    const int idx = atomicAdd(&pw_cnt, 1);
                    pw_pl[idx] = pl;
                    pw_kk[idx] = k1v | (k2v << 16);
                } else {                       // rare: full exact scan
                    const int idx = atomicAdd(&fs_cnt, 1);
                    fs_pl[idx] = pl;
                }
            }
        }
    }
    __syncthreads();

    const int pwc = pw_cnt;
    const int fsc = fs_cnt;

    // ---- inline PAIRWISE resolve: exact np-score of k1,k2 only ----------
    // wave-parallel, no barriers; verbatim np arithmetic + index tie-break.
    for (int i = w; i < pwc; i += 4) {
        const int pl = pw_pl[i];
        const int kk = pw_kk[i];
        const int ka = kk & 0xffff, kb = kk >> 16;
        const int sp = sp0 + pl;
        const float myx = x[(size_t)b * XSTRIDE + (size_t)lane * HW + sp];
        // Ap = np.sum(x**2) in numpy pairwise-8 order (verified grouping)
        float r8[8];
#pragma unroll
        for (int i0 = 0; i0 < 8; ++i0) {
            const float v = __shfl(myx, i0, 64);
            r8[i0] = __fmul_rn(v, v);
        }
#pragma unroll
        for (int j = 1; j < 8; ++j)
#pragma unroll
            for (int i0 = 0; i0 < 8; ++i0) {
                const float v = __shfl(myx, 8 * j + i0, 64);
                r8[i0] = r8[i0] + __fmul_rn(v, v);
            }
        const float Ap = ((r8[0] + r8[1]) + (r8[2] + r8[3])) + ((r8[4] + r8[5]) + (r8[6] + r8[7]));
        float Ba = 0.f, Bb = 0.f;              // sequential-d FMA chains (np)
#pragma unroll 8
        for (int d = 0; d < D; ++d) {
            const float xd = __shfl(myx, d, 64);
            Ba = __builtin_fmaf(xd, e[d * K + ka], Ba);
            Bb = __builtin_fmaf(xd, e[d * K + kb], Bb);
        }
        const float da = __builtin_fmaf(-2.f, Ba, Ap) + (-2.0f * c2n[ka]);
        const float db = __builtin_fmaf(-2.f, Bb, Ap) + (-2.0f * c2n[kb]);
        const int winner = (db < da || (db == da && kb < ka)) ? kb : ka;
        if (lane == 0) bk_lds[pl] = winner;    // disjoint per-wave writes
    }
    __syncthreads();                           // pairwise writes + xt reuse

    // ---- inline FULL-SCAN resolve (rare): R12-proven block-cooperative ---
    // scratch carved from the dead xt tile (rows 0,2,4 disjoint).
    {
        float* rs   = (float*)&xt[0][0];       // 256 floats
        int*   rk   = (int*)&xt[2][0];         // 256 ints
        float* xlds = (float*)&xt[4][0];       // 64 floats
        for (int i = 0; i < fsc; ++i) {
            const int pl = fs_pl[i];
            const int sp = sp0 + pl;
            if (t < 64)
                xlds[t] = x[(size_t)b * XSTRIDE + (size_t)t * HW + sp];
            __syncthreads();
            float r8[8];
#pragma unroll
            for (int i0 = 0; i0 < 8; ++i0) {
                const float v = xlds[i0];
                r8[i0] = __fmul_rn(v, v);
            }
#pragma unroll
            for (int j = 1; j < 8; ++j)
#pragma unroll
                for (int i0 = 0; i0 < 8; ++i0) {
                    const float v = xlds[8 * j + i0];
                    r8[i0] = r8[i0] + __fmul_rn(v, v);
                }
            const float Ap = ((r8[0] + r8[1]) + (r8[2] + r8[3])) + ((r8[4] + r8[5]) + (r8[6] + r8[7]));
            float bs = 3.4e38f; int bk = 0x7fffffff;
#pragma unroll
            for (int j = 0; j < 4; ++j) {
                const int k = t + 256 * j;     // ascending k per thread
                float acc2 = 0.f;
#pragma unroll 8
                for (int d = 0; d < D; ++d)    // sequential-k FMA chain (np)
                    acc2 = __builtin_fmaf(xlds[d], e[d * K + k], acc2);
                const float c2k = -2.0f * c2n[k];
                const float sc = __builtin_fmaf(-2.f, acc2, Ap) + c2k;
                if (sc < bs || (sc == bs && k < bk)) { bs = sc; bk = k; }
            }
            rs[t] = bs; rk[t] = bk;
            __syncthreads();
            for (int off = 128; off > 0; off >>= 1) {
                if (t < off) {
                    const float so = rs[t + off]; const int ko = rk[t + off];
                    if (so < rs[t] || (so == rs[t] && ko < rk[t])) { rs[t] = so; rk[t] = ko; }
                }
                __syncthreads();
            }
            if (t == 0) bk_lds[pl] = rk[0];    // exact index replaces approx
            __syncthreads();
        }
    }

    // ---- vectorized STE write: thread = 4 consecutive sp x 8 channels ----
    // float4 x re-read (L2-hot), scalar e-gather (L2-resident), float4 store
    // (1 KB/wave-op). Per-element fl(x + fl(q-x)) unchanged => bit-exact.
    {
        const int spq = t & 31;                // sp quad
        const int cg = t >> 5;                 // channel group 0..7
        const int pl0 = spq * 4;
        const int bk0 = bk_lds[pl0 + 0];
        const int bk1 = bk_lds[pl0 + 1];
        const int bk2 = bk_lds[pl0 + 2];
        const int bk3 = bk_lds[pl0 + 3];
        const size_t base = (size_t)b * XSTRIDE + sp0 + pl0;
#pragma unroll
        for (int i = 0; i < 8; ++i) {
            const int c = cg * 8 + i;
            const vfloat4 xq = *(const vfloat4*)(x + base + (size_t)c * HW);
            vfloat4 qv;
            qv[0] = e[c * K + bk0];
            qv[1] = e[c * K + bk1];
            qv[2] = e[c * K + bk2];
            qv[3] = e[c * K + bk3];
            vfloat4 o;
#pragma unroll
            for (int j = 0; j < 4; ++j)
                o[j] = xq[j] + (qv[j] - xq[j]);   // np STE: fl(x + fl(q-x))
            *(vfloat4*)(out + base + (size_t)c * HW) = o;
        }
    }
}

extern "C" void kernel_launch(void* const* d_in, const int* in_sizes, int n_in,
                              void* d_out, int out_size, void* d_ws, size_t ws_size,
                              hipStream_t stream) {
    const float* x = (const float*)d_in[0];
    const float* e = (const float*)d_in[1];
    float* out = (float*)d_out;

    char* ws = (char*)d_ws;                          // ~260 KB used
    unsigned short* ebf = (unsigned short*)ws;       // 256 KB B-fragments
    float* c2n = (float*)(ws + 262144);              // 4 KB  (-0.5*sum e^2)

    vq_prep<<<32, 256, 0, stream>>>(e, ebf, c2n);
    vq_main<<<NPOS / 128, 256, 0, stream>>>(x, e, ebf, c2n, out);
}